// Round 3
// baseline (1405.299 us; speedup 1.0000x reference)
//
#include <hip/hip_runtime.h>

// Group VQ: x [B=16, C=2, F=256, T=4000] fp32, codebooks [G=8, K=1024, D=64] fp32.
// Feature cf = c*256+f = g*64+d (g major). Token (b,g,t): x[b, g*64+dd, t], dd-stride T.
// Output = concat(x_q, x_q_detach); forward x_q = fl(x + fl(q - x)), x_q_detach = q.
//
// Correctness-critical: argmin must match the fp32 reference pipeline, including
// near-tie resolution. We replicate: dist = fl( fl(x2 - 2*dot) + e2 ) with
//   x2,e2 = numpy pairwise-8 sums of ROUNDED squares (anti-fusion barriers),
//   dot   = 4-accumulator stride-4 FMA chain, combined (l0+l2)+(l1+l3) (SSE tree),
//   argmin with strict < (first index wins ties). NO exact/fp64 tiebreak --
//   R0 failed (absmax 2.74) precisely because an exact tiebreak resolves
//   fp32-borderline tokens differently from the fp32 references.

#define TPB 256
constexpr int Bb = 16, Tt = 4000;
constexpr int G = 8, K = 1024, D = 64;
constexpr long long OUT_HALF = 16LL * 512LL * 4000LL;   // 32,768,000

__global__ __launch_bounds__(TPB, 4)
void gvq_kernel(const float* __restrict__ x, const float* __restrict__ cb,
                float* __restrict__ out)
{
    __shared__ float e2_lds[K];          // sum(e^2), numpy-pairwise rounding

    const int blk  = blockIdx.x;
    const int tb   = blk & 15;           // 16 t-blocks of 256 per (b,g)
    const int pair = blk >> 4;           // 0..127
    const int g    = pair & 7;
    const int b    = pair >> 3;
    const int tid  = threadIdx.x;

    const float* __restrict__ cbg = cb + (size_t)g * K * D;

    // ---- e2[k] = np.sum(e*e) : pairwise base case n=64 (8 accs stride 8,
    //      rounded products, tree combine). Anti-fusion barrier on each product.
    for (int kk = tid; kk < K; kk += TPB) {
        const float* __restrict__ e = cbg + kk * D;
        float r[8];
        #pragma unroll
        for (int j = 0; j < 8; ++j) {
            float p = e[j] * e[j];
            asm volatile("" : "+v"(p));
            r[j] = p;
        }
        #pragma unroll
        for (int i = 1; i < 8; ++i) {
            #pragma unroll
            for (int j = 0; j < 8; ++j) {
                float p = e[8 * i + j] * e[8 * i + j];
                asm volatile("" : "+v"(p));
                r[j] += p;
            }
        }
        e2_lds[kk] = ((r[0] + r[1]) + (r[2] + r[3])) + ((r[4] + r[5]) + (r[6] + r[7]));
    }
    __syncthreads();

    const int t = tb * TPB + tid;
    if (t >= Tt) return;                 // tail: 4000 = 15*256 + 160

    // ---- token column into registers (coalesced across lanes along t) ----
    const size_t xbase = ((size_t)(b * 512 + g * 64)) * Tt + t;
    float xv[D];
    #pragma unroll
    for (int dd = 0; dd < D; ++dd) xv[dd] = x[xbase + (size_t)dd * Tt];

    // ---- x2 = np.sum(x*x) with identical pairwise scheme ----
    float x2;
    {
        float r[8];
        #pragma unroll
        for (int j = 0; j < 8; ++j) {
            float p = xv[j] * xv[j];
            asm volatile("" : "+v"(p));
            r[j] = p;
        }
        #pragma unroll
        for (int i = 1; i < 8; ++i) {
            #pragma unroll
            for (int j = 0; j < 8; ++j) {
                float p = xv[8 * i + j] * xv[8 * i + j];
                asm volatile("" : "+v"(p));
                r[j] += p;
            }
        }
        x2 = ((r[0] + r[1]) + (r[2] + r[3])) + ((r[4] + r[5]) + (r[6] + r[7]));
    }

    // ---- scan 1024 codes: dist = fl( fl(x2 - 2*dot) + e2 ), strict-< argmin ----
    float m1 = 3.4e38f;
    int   i1 = 0;
    for (int k = 0; k < K; ++k) {
        const float* __restrict__ e = cbg + k * D;   // wave-uniform -> s_load
        float l0 = 0.f, l1 = 0.f, l2 = 0.f, l3 = 0.f;
        #pragma unroll
        for (int dd = 0; dd < D; dd += 4) {
            l0 = __builtin_fmaf(e[dd + 0], xv[dd + 0], l0);
            l1 = __builtin_fmaf(e[dd + 1], xv[dd + 1], l1);
            l2 = __builtin_fmaf(e[dd + 2], xv[dd + 2], l2);
            l3 = __builtin_fmaf(e[dd + 3], xv[dd + 3], l3);
        }
        const float dot  = (l0 + l2) + (l1 + l3);    // SSE movehl/shuffle tree
        const float dist = (x2 - 2.0f * dot) + e2_lds[k];  // 2*dot exact; 2 rounds
        const bool lt = dist < m1;                   // tie -> earlier k (np.argmin)
        m1 = lt ? dist : m1;
        i1 = lt ? k    : i1;
    }

    // ---- gather winning row, write both outputs (coalesced along t) ----
    const float* __restrict__ q  = cbg + (size_t)i1 * D;
    float* __restrict__ o1 = out + xbase;
    float* __restrict__ o2 = out + OUT_HALF + xbase;
    #pragma unroll
    for (int dd = 0; dd < D; ++dd) {
        const float qa = q[dd];
        const float diff = qa - xv[dd];
        o1[(size_t)dd * Tt] = xv[dd] + diff;         // fl(x + fl(q - x))
        o2[(size_t)dd * Tt] = qa;
    }
}

extern "C" void kernel_launch(void* const* d_in, const int* in_sizes, int n_in,
                              void* d_out, int out_size, void* d_ws, size_t ws_size,
                              hipStream_t stream)
{
    const float* x  = (const float*)d_in[0];
    const float* cb = (const float*)d_in[1];
    float* out      = (float*)d_out;

    dim3 grid(16 * Bb * G);   // 2048 blocks of 256 threads
    dim3 block(TPB);
    hipLaunchKernelGGL(gvq_kernel, grid, block, 0, stream, x, cb, out);
}